// Round 7
// baseline (439.668 us; speedup 1.0000x reference)
//
#include <hip/hip_runtime.h>

typedef float f4 __attribute__((ext_vector_type(4)));
typedef short s4 __attribute__((ext_vector_type(4)));
typedef short s8 __attribute__((ext_vector_type(8)));
typedef unsigned u32;

#define HWD 1024
#define THW 8192
#define CVD 512
#define AFP 36

#define MFMA32 __builtin_amdgcn_mfma_f32_16x16x32_bf16

__device__ __forceinline__ f4 mfma1616(s4 a, s4 b, f4 c) {
#if __has_builtin(__builtin_amdgcn_mfma_f32_16x16x16_bf16)
    return __builtin_amdgcn_mfma_f32_16x16x16_bf16(a, b, c, 0, 0, 0);
#elif __has_builtin(__builtin_amdgcn_mfma_f32_16x16x16bf16_1k)
    return __builtin_amdgcn_mfma_f32_16x16x16bf16_1k(a, b, c, 0, 0, 0);
#else
    f4 d;
    asm volatile("v_mfma_f32_16x16x16_bf16 %0, %1, %2, %3"
                 : "=v"(d) : "v"(a), "v"(b), "v"(c));
    return d;
#endif
}

__device__ __forceinline__ u32 cvtpk(float a, float b) {
    u32 r;
    asm volatile("v_cvt_pk_bf16_f32 %0, %1, %2" : "=v"(r) : "v"(a), "v"(b));
    return r;   // lo16 = bf16(a), hi16 = bf16(b)
}
__device__ __forceinline__ float ubits(u32 u) {
    return __builtin_bit_cast(float, u);
}
__device__ __forceinline__ s8 frag2(const short* p) {
    return __builtin_shufflevector(*(const s4*)p, *(const s4*)(p + 4), 0,1,2,3,4,5,6,7);
}
__device__ __forceinline__ s4 pks4(u32 a, u32 b) {
    return __builtin_bit_cast(s4, make_uint2(a, b));
}

// ============ combined prep: mv->bf16 | out init | feat rows ============
__global__ __launch_bounds__(256)
void mr_prep(const float* __restrict__ mv, const float* __restrict__ qv,
             const float* __restrict__ mk,
             short* __restrict__ mvH,
             short* __restrict__ ftH, short* __restrict__ ftL,
             float* __restrict__ out)
{
    __shared__ float mkT[16][260];
    const int bid = blockIdx.x, t = threadIdx.x;
    if (bid < 8192) {
        // ---- mv fp32 -> bf16 (hi only; lo-product dropped in readout) ----
        int i = bid * 256 + t;
        f4 v = ((const f4*)mv)[i];
        ((uint2*)mvH)[i] = make_uint2(cvtpk(v[0], v[1]), cvtpk(v[2], v[3]));
    } else if (bid < 10240) {
        // ---- out init: zero mem half, copy qv half ----
        int idx = (bid - 8192) * 256 + t;
        int b = idx >> 18, r = idx & 262143, ch = r >> 8;
        f4 v = f4{0.f, 0.f, 0.f, 0.f};
        if (ch >= CVD) v = ((const f4*)qv)[(b << 17) + ((ch - CVD) << 8) + (r & 255)];
        ((f4*)out)[idx] = v;
    } else {
        // ---- feat rows: (mk^3, mk) bf16 hi/lo, k-contiguous ----
        const int fbid = bid - 10240;                 // 0..255
        const int chunk = fbid & 31, h = (fbid >> 5) & 3, b = fbid >> 7;
        const float* src = mk + (size_t)(b * 64 + h * 16) * THW + chunk * 256;
#pragma unroll
        for (int i = 0; i < 4; ++i) {
            int q = t + 256 * i;
            int c = q >> 6, j = q & 63;
            *(f4*)&mkT[c][j * 4] = *(const f4*)(src + (size_t)c * THW + j * 4);
        }
        __syncthreads();
        u32 uH[16], uL[16];
#pragma unroll
        for (int c = 0; c < 16; ++c) {
            float x = mkT[c][t];
            float x3 = x * x * x;
            u32 hh = cvtpk(x3, x);
            float r3 = x3 - ubits(hh << 16);
            float r1 = x  - ubits(hh & 0xffff0000u);
            uH[c] = hh;
            uL[c] = cvtpk(r3, r1);
        }
        size_t row = ((size_t)(b * 4 + h) * THW + chunk * 256 + t) * 32;
        uint4* dH = (uint4*)(ftH + row);
        uint4* dL = (uint4*)(ftL + row);
#pragma unroll
        for (int k = 0; k < 4; ++k) {
            dH[k] = make_uint4(uH[4*k], uH[4*k+1], uH[4*k+2], uH[4*k+3]);
            dL[k] = make_uint4(uL[4*k], uL[4*k+1], uL[4*k+2], uL[4*k+3]);
        }
    }
}

// ============ fused main: zero-LDS zero-barrier main loop ============
// 512 thr = 8 waves = 4 n-slices (ws) x 2 m-halves (wm). Block: 32 m x 2048 n
// x 256 cv (hp half). Each wave: sim(4 heads, K=32 MFMA) -> in-register
// softmax -> aff already in K=16 B-frag layout -> readout K=16 MFMA.
__global__ __launch_bounds__(512, 4)
void mr_main(const float* __restrict__ qk, const float* __restrict__ qe,
             const float* __restrict__ ms,
             const short* __restrict__ mvH,
             const short* __restrict__ ftH, const short* __restrict__ ftL,
             float* __restrict__ out)
{
    __shared__ __align__(16) short wSH[4][32][AFP];   // 9216 B
    __shared__ __align__(16) short wSL[4][32][AFP];   // 9216 B
    __shared__ float msS[2048];                        // 8192 B (pre-scaled)
    __shared__ float bS[4][32];                        //  512 B

    // XCD swizzle: 2 XCDs share one 2048-n group (mv slice 2 MB -> L2-resident)
    const int bid  = blockIdx.x;                 // 512 blocks
    const int wid  = (bid & 7) * 64 + (bid >> 3);
    const int ncg  = wid >> 7;                   // 4 n-groups of 2048
    const int rest = wid & 127;
    const int mt0  = rest & 31;
    const int hp   = (rest >> 5) & 1;
    const int b    = rest >> 6;
    const int m0   = mt0 * 32;
    const int n0   = ncg * 2048;

    const int t  = threadIdx.x;
    const int wv = t >> 6, l = t & 63, lr = l & 15, lg = l >> 4;
    const int ws = wv & 3;       // wave's n-slice (512 n each)
    const int wm = wv >> 2;      // wave's m-half

    // ---- setup: weights+bias (t<128) and ms staging (all 512) ----
    if (t < 128) {
        const int h = t >> 5, m = t & 31;
        const float* qkp = qk + (size_t)(b * 64 + h * 16) * HWD + m0 + m;
        const float* qep = qe + (size_t)(b * 64 + h * 16) * HWD + m0 + m;
        float bias = 0.f;
#pragma unroll
        for (int c = 0; c < 16; ++c) {
            float kv = qkp[(size_t)c * HWD];
            float ev = qep[(size_t)c * HWD];
            float w0 = -ev, w1 = 2.f * kv * ev;
            u32 hh = cvtpk(w0, w1);
            float r0 = w0 - ubits(hh << 16);
            float r1 = w1 - ubits(hh & 0xffff0000u);
            *(u32*)&wSH[h][m][2 * c] = hh;
            *(u32*)&wSL[h][m][2 * c] = cvtpk(r0, r1);
            bias -= ev * kv * kv * kv;
        }
        bS[h][m] = bias;
    }
    {   // ms, pre-scaled by 1/sqrt(CK)=0.125
        f4 v = ((const f4*)(ms + (size_t)b * THW + n0))[t];
        ((f4*)msS)[t] = v * 0.125f;
    }
    __syncthreads();

    // loop-invariant: w-hi fragments + bias in registers (w-lo stays in LDS)
    s8 wHr[4];
    float biasr[4];
#pragma unroll
    for (int h = 0; h < 4; ++h) {
        wHr[h]   = frag2(&wSH[h][wm * 16 + lr][lg * 8]);
        biasr[h] = bS[h][wm * 16 + lr];
    }

    f4 acc[16];
#pragma unroll
    for (int ct = 0; ct < 16; ++ct) acc[ct] = f4{0.f, 0.f, 0.f, 0.f};

    const int nb0 = n0 + ws * 512;               // wave's absolute n-base
    const short* fbH = ftH + ((size_t)(b * 4) * THW + nb0 + lr) * 32 + lg * 8;
    const short* fbL = ftL + ((size_t)(b * 4) * THW + nb0 + lr) * 32 + lg * 8;
    const short* mvb = mvH + (size_t)(b * CVD + hp * 256 + lr) * THW + nb0 + lg * 4;

    for (int s = 0; s < 32; ++s) {
        const int nn = s * 16;                   // iter offset within wave slice

        // ===== sim: per-head K=32 MFMA (bias as C-in), 3-product hi/lo =====
        f4 sacc[4];
#pragma unroll
        for (int h = 0; h < 4; ++h) {
            s8 fH = *(const s8*)(fbH + (size_t)h * (THW * 32) + nn * 32);
            s8 fL = *(const s8*)(fbL + (size_t)h * (THW * 32) + nn * 32);
            s8 wL = frag2(&wSL[h][wm * 16 + lr][lg * 8]);
            f4 sa = f4{biasr[h], biasr[h], biasr[h], biasr[h]};
            sa = MFMA32(fH, wHr[h], sa, 0, 0, 0);
            sa = MFMA32(fL, wHr[h], sa, 0, 0, 0);
            sa = MFMA32(fH, wL,     sa, 0, 0, 0);
            sacc[h] = sa;
        }

        // ===== softmax over heads, in-lane; n = nb0+nn+lg*4+r, m = m0+wm*16+lr =====
        f4 msv = *(const f4*)&msS[ws * 512 + nn + lg * 4];
        float a0[4], a1[4];
#pragma unroll
        for (int r = 0; r < 4; ++r) {
            float x0 = sacc[0][r] * msv[r], x1 = sacc[1][r] * msv[r];
            float x2 = sacc[2][r] * msv[r], x3 = sacc[3][r] * msv[r];
            float mx = fmaxf(fmaxf(x0, x1), fmaxf(x2, x3));
            float e0 = __expf(x0 - mx), e1 = __expf(x1 - mx);
            float e2 = __expf(x2 - mx), e3 = __expf(x3 - mx);
            float rin = 1.f / (e0 + e1 + e2 + e3);
            a0[r] = (hp ? e2 : e0) * rin;        // local head 0 of this hp half
            a1[r] = (hp ? e3 : e1) * rin;        // local head 1
        }
        // pack: sim-D layout == K=16 B-frag layout -> direct register reuse
        u32 p001 = cvtpk(a0[0], a0[1]), p023 = cvtpk(a0[2], a0[3]);
        u32 p101 = cvtpk(a1[0], a1[1]), p123 = cvtpk(a1[2], a1[3]);
        s4 bH0 = pks4(p001, p023);
        s4 bH1 = pks4(p101, p123);
        s4 bL0 = pks4(cvtpk(a0[0] - ubits(p001 << 16), a0[1] - ubits(p001 & 0xffff0000u)),
                      cvtpk(a0[2] - ubits(p023 << 16), a0[3] - ubits(p023 & 0xffff0000u)));
        s4 bL1 = pks4(cvtpk(a1[0] - ubits(p101 << 16), a1[1] - ubits(p101 & 0xffff0000u)),
                      cvtpk(a1[2] - ubits(p123 << 16), a1[3] - ubits(p123 & 0xffff0000u)));

        // ===== readout: K=16 MFMA, aff hi/lo x mv-hi (2 products) =====
#pragma unroll
        for (int ct = 0; ct < 16; ++ct) {
            s4 aH = *(const s4*)(mvb + (size_t)ct * 16 * THW + nn);
            s4 bh = (ct < 8) ? bH0 : bH1;
            s4 bl = (ct < 8) ? bL0 : bL1;
            acc[ct] = mfma1616(aH, bh, acc[ct]);
            acc[ct] = mfma1616(aH, bl, acc[ct]);
        }
    }

    // ---- epilogue: combine partials (2 ncg x 4 ws per address) ----
    float* ob = out + (size_t)b * (2 * CVD * HWD)
                + (size_t)(hp * 256) * HWD + m0 + wm * 16 + lr;
#pragma unroll
    for (int ct = 0; ct < 16; ++ct)
#pragma unroll
        for (int r = 0; r < 4; ++r)
#if defined(__HIP_PLATFORM_AMD__)
            unsafeAtomicAdd(ob + (size_t)(ct * 16 + lg * 4 + r) * HWD, acc[ct][r]);
#else
            atomicAdd(ob + (size_t)(ct * 16 + lg * 4 + r) * HWD, acc[ct][r]);
#endif
}

extern "C" void kernel_launch(void* const* d_in, const int* in_sizes, int n_in,
                              void* d_out, int out_size, void* d_ws, size_t ws_size,
                              hipStream_t stream) {
    (void)in_sizes; (void)n_in; (void)out_size; (void)ws_size;
    const float* mk = (const float*)d_in[0];
    const float* qk = (const float*)d_in[1];
    const float* ms = (const float*)d_in[2];
    const float* qe = (const float*)d_in[3];
    const float* mv = (const float*)d_in[4];
    const float* qv = (const float*)d_in[5];
    float* out = (float*)d_out;

    // ws layout: mvH 16MiB | ftH 4MiB | ftL 4MiB  (total 24 MiB)
    short* mvH = (short*)d_ws;
    short* ftH = (short*)((char*)d_ws + 16777216);
    short* ftL = (short*)((char*)d_ws + 20971520);

    mr_prep<<<10496, 256, 0, stream>>>(mv, qv, mk, mvH, ftH, ftL, out);
    mr_main<<<512, 512, 0, stream>>>(qk, qe, ms, mvH, ftH, ftL, out);
}

// Round 9
// 400.150 us; speedup vs baseline: 1.0988x; 1.0988x over previous
//
#include <hip/hip_runtime.h>

typedef float f4 __attribute__((ext_vector_type(4)));
typedef short s4 __attribute__((ext_vector_type(4)));
typedef short s8 __attribute__((ext_vector_type(8)));
typedef unsigned u32;

#define HWD 1024
#define THW 8192
#define CVD 512
#define AFP 36

#define MFMA32 __builtin_amdgcn_mfma_f32_16x16x32_bf16

__device__ __forceinline__ u32 cvtpk(float a, float b) {
    u32 r;
    asm("v_cvt_pk_bf16_f32 %0, %1, %2" : "=v"(r) : "v"(a), "v"(b));
    return r;   // lo16 = bf16(a), hi16 = bf16(b)
}
__device__ __forceinline__ float ubits(u32 u) {
    return __builtin_bit_cast(float, u);
}
__device__ __forceinline__ s8 frag2(const short* p) {
    return __builtin_shufflevector(*(const s4*)p, *(const s4*)(p + 4), 0,1,2,3,4,5,6,7);
}

// ============ combined prep: mv->bf16 | out init | feat rows ============
__global__ __launch_bounds__(256)
void mr_prep(const float* __restrict__ mv, const float* __restrict__ qv,
             const float* __restrict__ mk,
             short* __restrict__ mvH,
             short* __restrict__ ftH, short* __restrict__ ftL,
             float* __restrict__ out)
{
    __shared__ float mkT[16][260];
    const int bid = blockIdx.x, t = threadIdx.x;
    if (bid < 8192) {
        // ---- mv fp32 -> bf16 hi (lo-product dropped in readout) ----
        int i = bid * 256 + t;
        f4 v = ((const f4*)mv)[i];
        ((uint2*)mvH)[i] = make_uint2(cvtpk(v[0], v[1]), cvtpk(v[2], v[3]));
    } else if (bid < 10240) {
        // ---- out init: zero mem half, copy qv half ----
        int idx = (bid - 8192) * 256 + t;
        int b = idx >> 18, r = idx & 262143, ch = r >> 8;
        f4 v = f4{0.f, 0.f, 0.f, 0.f};
        if (ch >= CVD) v = ((const f4*)qv)[(b << 17) + ((ch - CVD) << 8) + (r & 255)];
        ((f4*)out)[idx] = v;
    } else {
        // ---- feat rows: (mk^3, mk) bf16 hi/lo, k-contiguous ----
        const int fbid = bid - 10240;                 // 0..255
        const int chunk = fbid & 31, h = (fbid >> 5) & 3, b = fbid >> 7;
        const float* src = mk + (size_t)(b * 64 + h * 16) * THW + chunk * 256;
#pragma unroll
        for (int i = 0; i < 4; ++i) {
            int q = t + 256 * i;
            int c = q >> 6, j = q & 63;
            *(f4*)&mkT[c][j * 4] = *(const f4*)(src + (size_t)c * THW + j * 4);
        }
        __syncthreads();
        u32 uH[16], uL[16];
#pragma unroll
        for (int c = 0; c < 16; ++c) {
            float x = mkT[c][t];
            float x3 = x * x * x;
            u32 hh = cvtpk(x3, x);
            float r3 = x3 - ubits(hh << 16);
            float r1 = x  - ubits(hh & 0xffff0000u);
            uH[c] = hh;
            uL[c] = cvtpk(r3, r1);
        }
        size_t row = ((size_t)(b * 4 + h) * THW + chunk * 256 + t) * 32;
        uint4* dH = (uint4*)(ftH + row);
        uint4* dL = (uint4*)(ftL + row);
#pragma unroll
        for (int k = 0; k < 4; ++k) {
            dH[k] = make_uint4(uH[4*k], uH[4*k+1], uH[4*k+2], uH[4*k+3]);
            dL[k] = make_uint4(uL[4*k], uL[4*k+1], uL[4*k+2], uL[4*k+3]);
        }
    }
}

// ============ fused main: r4 structure + dbuf(1 barrier) + prefetch + setprio ============
// 512 thr = 8 waves. Block: 64 m x 1024 n x 256 cv (hp half).
// sim roles: (nt,mq) quadrant of 32n x 64m. readout roles: (hl,cvh,mh).
__global__ __launch_bounds__(512, 4)
void mr_main(const float* __restrict__ qk, const float* __restrict__ qe,
             const float* __restrict__ ms,
             const short* __restrict__ mvH,
             const short* __restrict__ ftH, const short* __restrict__ ftL,
             float* __restrict__ out)
{
    // aff double-buffer overlays setup-only w tiles
    __shared__ __align__(16) char ovl[73728];
    __shared__ __align__(16) float msS[1024];
    __shared__ float bS[4][64];

    short (*aff)[2][2][64][AFP] = (short (*)[2][2][64][AFP])ovl;  // [buf][hilo][hl][m][n]
    short (*wHs)[64][AFP] = (short (*)[64][AFP])ovl;              // setup only
    short (*wLs)[64][AFP] = (short (*)[64][AFP])(ovl + 18432);    // setup only

    // bijective XCD swizzle: 64 consecutive blocks (one n-chunk) per XCD
    const int bid  = blockIdx.x;                 // 512 blocks
    const int wid  = (bid & 7) * 64 + (bid >> 3);
    const int nc   = wid >> 6;                   // 8 n-chunks of 1024
    const int rest = wid & 63;
    const int mt0  = rest & 15;
    const int hp   = (rest >> 4) & 1;
    const int b    = rest >> 5;
    const int m0   = mt0 * 64;
    const int n0   = nc * 1024;

    const int t  = threadIdx.x;
    const int wv = t >> 6, l = t & 63, lr = l & 15, lg = l >> 4;
    const int nt = wv & 1, mq = wv >> 1;                       // sim
    const int hl = wv & 1, cvh = (wv >> 1) & 1, mh = wv >> 2;  // readout

    // ---- setup: weights hi/lo + bias + pre-scaled ms ----
    if (t < 256) {
        const int h = t >> 6, m = t & 63;
        const float* qkp = qk + (size_t)(b * 64 + h * 16) * HWD + m0 + m;
        const float* qep = qe + (size_t)(b * 64 + h * 16) * HWD + m0 + m;
        float bias = 0.f;
#pragma unroll
        for (int c = 0; c < 16; ++c) {
            float kv = qkp[(size_t)c * HWD];
            float ev = qep[(size_t)c * HWD];
            float w0 = -ev, w1 = 2.f * kv * ev;
            u32 hh = cvtpk(w0, w1);
            float r0 = w0 - ubits(hh << 16);
            float r1 = w1 - ubits(hh & 0xffff0000u);
            *(u32*)&wHs[h][m][2 * c] = hh;
            *(u32*)&wLs[h][m][2 * c] = cvtpk(r0, r1);
            bias -= ev * kv * kv * kv;
        }
        bS[h][m] = bias;
        // ms pre-scaled by 0.125*log2(e): softmax runs in exp2 domain
        f4 v = ((const f4*)(ms + (size_t)b * THW + n0))[t];
        ((f4*)msS)[t] = v * 0.18033688011112042f;
    }
    __syncthreads();

    // loop-invariant fragments -> registers (wS region is then reused as aff)
    s8 wHr[4], wLr[4];
    float biasr[4];
#pragma unroll
    for (int h = 0; h < 4; ++h) {
        wHr[h]   = frag2(&wHs[h][mq * 16 + lr][lg * 8]);
        wLr[h]   = frag2(&wLs[h][mq * 16 + lr][lg * 8]);
        biasr[h] = bS[h][mq * 16 + lr];
    }
    __syncthreads();

    f4 acc[4][2];
#pragma unroll
    for (int ct = 0; ct < 4; ++ct) {
        acc[ct][0] = f4{0.f, 0.f, 0.f, 0.f};
        acc[ct][1] = f4{0.f, 0.f, 0.f, 0.f};
    }

    const size_t ftoff = ((size_t)(b * 4) * THW + n0 + nt * 16 + lr) * 32 + lg * 8;
    const short* fH0 = ftH + ftoff;
    const short* fL0 = ftL + ftoff;
    const short* mvb = mvH + (size_t)(b * CVD + hp * 256 + hl * 128 + cvh * 64 + lr) * THW
                       + n0 + lg * 8;

    // preload ft for s=0
    s8 fHc[4], fLc[4];
#pragma unroll
    for (int h = 0; h < 4; ++h) {
        fHc[h] = *(const s8*)(fH0 + (size_t)h * (THW * 32));
        fLc[h] = *(const s8*)(fL0 + (size_t)h * (THW * 32));
    }

    for (int s = 0; s < 32; ++s) {
        const int p = s & 1;

        // mv loads for this iter (consumed after the barrier -> in flight across it)
        s8 aH[4];
#pragma unroll
        for (int ct = 0; ct < 4; ++ct)
            aH[ct] = *(const s8*)(mvb + (size_t)ct * 16 * THW + s * 32);

        // ===== sim: 4 heads x 3-product hi/lo, bias as C-in =====
        f4 sacc[4];
        __builtin_amdgcn_s_setprio(1);
#pragma unroll
        for (int h = 0; h < 4; ++h) {
            f4 sa = f4{biasr[h], biasr[h], biasr[h], biasr[h]};
            sa = MFMA32(fHc[h], wHr[h], sa, 0, 0, 0);
            sa = MFMA32(fLc[h], wHr[h], sa, 0, 0, 0);
            sa = MFMA32(fHc[h], wLr[h], sa, 0, 0, 0);
            sacc[h] = sa;
        }
        __builtin_amdgcn_s_setprio(0);

        // prefetch ft for next iter (latency hidden under softmax+barrier+readout)
        const int sn = (s < 31) ? s + 1 : 31;
        s8 fHn[4], fLn[4];
#pragma unroll
        for (int h = 0; h < 4; ++h) {
            fHn[h] = *(const s8*)(fH0 + (size_t)h * (THW * 32) + (size_t)sn * 1024);
            fLn[h] = *(const s8*)(fL0 + (size_t)h * (THW * 32) + (size_t)sn * 1024);
        }

        // ===== softmax over heads (exp2 domain), in-lane =====
        f4 msv = *(const f4*)&msS[s * 32 + nt * 16 + lg * 4];
        float a0[4], a1[4];
#pragma unroll
        for (int r = 0; r < 4; ++r) {
            float x0 = sacc[0][r] * msv[r], x1 = sacc[1][r] * msv[r];
            float x2 = sacc[2][r] * msv[r], x3 = sacc[3][r] * msv[r];
            float mx = fmaxf(fmaxf(x0, x1), fmaxf(x2, x3));
            float e0 = __builtin_exp2f(x0 - mx), e1 = __builtin_exp2f(x1 - mx);
            float e2 = __builtin_exp2f(x2 - mx), e3 = __builtin_exp2f(x3 - mx);
            float rin = 1.f / (e0 + e1 + e2 + e3);
            a0[r] = (hp ? e2 : e0) * rin;
            a1[r] = (hp ? e3 : e1) * rin;
        }
        // pack aff -> bf16 hi/lo, write B-frag layout tile [m][n]
        u32 p001 = cvtpk(a0[0], a0[1]), p023 = cvtpk(a0[2], a0[3]);
        u32 p101 = cvtpk(a1[0], a1[1]), p123 = cvtpk(a1[2], a1[3]);
        u32 l001 = cvtpk(a0[0] - ubits(p001 << 16), a0[1] - ubits(p001 & 0xffff0000u));
        u32 l023 = cvtpk(a0[2] - ubits(p023 << 16), a0[3] - ubits(p023 & 0xffff0000u));
        u32 l101 = cvtpk(a1[0] - ubits(p101 << 16), a1[1] - ubits(p101 & 0xffff0000u));
        u32 l123 = cvtpk(a1[2] - ubits(p123 << 16), a1[3] - ubits(p123 & 0xffff0000u));
        {
            const int mrow = mq * 16 + lr, nn = nt * 16 + lg * 4;
            *(uint2*)&aff[p][0][0][mrow][nn] = make_uint2(p001, p023);
            *(uint2*)&aff[p][1][0][mrow][nn] = make_uint2(l001, l023);
            *(uint2*)&aff[p][0][1][mrow][nn] = make_uint2(p101, p123);
            *(uint2*)&aff[p][1][1][mrow][nn] = make_uint2(l101, l123);
        }
        __syncthreads();   // single barrier: next iter writes buf p^1, safe

        // ===== readout: aff hi/lo x mv-hi (2 products, K=32) =====
        s8 bH[2], bL[2];
#pragma unroll
        for (int mt = 0; mt < 2; ++mt) {
            bH[mt] = frag2(&aff[p][0][hl][mh * 32 + mt * 16 + lr][lg * 8]);
            bL[mt] = frag2(&aff[p][1][hl][mh * 32 + mt * 16 + lr][lg * 8]);
        }
        __builtin_amdgcn_s_setprio(1);
#pragma unroll
        for (int ct = 0; ct < 4; ++ct)
#pragma unroll
            for (int mt = 0; mt < 2; ++mt) {
                acc[ct][mt] = MFMA32(aH[ct], bH[mt], acc[ct][mt], 0, 0, 0);
                acc[ct][mt] = MFMA32(aH[ct], bL[mt], acc[ct][mt], 0, 0, 0);
            }
        __builtin_amdgcn_s_setprio(0);

        // rotate prefetch regs (static indices only)
#pragma unroll
        for (int h = 0; h < 4; ++h) { fHc[h] = fHn[h]; fLc[h] = fLn[h]; }
    }

    // ---- epilogue: combine 8 n-chunk partials via hw fp32 atomics ----
    float* ob = out + (size_t)b * (2 * CVD * HWD)
                + (size_t)(hp * 256 + hl * 128 + cvh * 64) * HWD + m0 + mh * 32 + lr;
#pragma unroll
    for (int ct = 0; ct < 4; ++ct)
#pragma unroll
        for (int mt = 0; mt < 2; ++mt)
#pragma unroll
            for (int r = 0; r < 4; ++r)
#if defined(__HIP_PLATFORM_AMD__)
                unsafeAtomicAdd(ob + (size_t)(ct * 16 + lg * 4 + r) * HWD + mt * 16,
                                acc[ct][mt][r]);
#else
                atomicAdd(ob + (size_t)(ct * 16 + lg * 4 + r) * HWD + mt * 16,
                          acc[ct][mt][r]);
#endif
}

extern "C" void kernel_launch(void* const* d_in, const int* in_sizes, int n_in,
                              void* d_out, int out_size, void* d_ws, size_t ws_size,
                              hipStream_t stream) {
    (void)in_sizes; (void)n_in; (void)out_size; (void)ws_size;
    const float* mk = (const float*)d_in[0];
    const float* qk = (const float*)d_in[1];
    const float* ms = (const float*)d_in[2];
    const float* qe = (const float*)d_in[3];
    const float* mv = (const float*)d_in[4];
    const float* qv = (const float*)d_in[5];
    float* out = (float*)d_out;

    // ws layout: mvH 16MiB | ftH 4MiB | ftL 4MiB  (total 24 MiB)
    short* mvH = (short*)d_ws;
    short* ftH = (short*)((char*)d_ws + 16777216);
    short* ftL = (short*)((char*)d_ws + 20971520);

    mr_prep<<<10496, 256, 0, stream>>>(mv, qv, mk, mvH, ftH, ftL, out);
    mr_main<<<512, 512, 0, stream>>>(qk, qe, ms, mvH, ftH, ftL, out);
}